// Round 1
// baseline (5567.194 us; speedup 1.0000x reference)
//
#include <hip/hip_runtime.h>

#define NN 100000
#define NE 3200000
#define DD 128

// deg[i] = 1 (self loop), then += 1 per incoming edge
__global__ __launch_bounds__(256) void k_init_deg(int* __restrict__ deg) {
    int i = blockIdx.x * 256 + threadIdx.x;
    if (i < NN) deg[i] = 1;
}

__global__ __launch_bounds__(256) void k_count_deg(const int* __restrict__ dst,
                                                   int* __restrict__ deg) {
    int e = blockIdx.x * 256 + threadIdx.x;
    if (e < NE) atomicAdd(&deg[dst[e]], 1);
}

// g = (x @ W) * rsqrt(deg[row]); also seed out with g (self-loop term).
// Block: 256 threads -> 32-row x 128-col tile. W fully staged in LDS (64KB).
// Thread (ty,tx) computes a 4x4 micro-tile: 16 FMA per (4 xs + 1 float4 W) LDS reads.
// NN % 32 == 0 -> no row bounds checks.
__global__ __launch_bounds__(256) void k_gemm_scale(
    const float* __restrict__ x, const float* __restrict__ W,
    const int* __restrict__ deg, float* __restrict__ g, float* __restrict__ out) {
    __shared__ float Wl[DD * DD];    // 64 KB
    __shared__ float xs[32][DD];     // 16 KB
    for (int t = threadIdx.x; t < DD * DD / 4; t += 256)
        ((float4*)Wl)[t] = ((const float4*)W)[t];
    const int row0 = blockIdx.x * 32;
    {
        const float4* xv = (const float4*)(x + (size_t)row0 * DD);
        float4* xsv = (float4*)&xs[0][0];
        for (int v = threadIdx.x; v < 32 * DD / 4; v += 256) xsv[v] = xv[v];
    }
    __syncthreads();
    const int tx = threadIdx.x & 31;
    const int ty = threadIdx.x >> 5;
    const int c0 = tx * 4;
    const int r0 = ty * 4;
    float acc[4][4] = {};
#pragma unroll 4
    for (int k = 0; k < DD; ++k) {
        float4 w = *(const float4*)&Wl[k * DD + c0];
#pragma unroll
        for (int j = 0; j < 4; ++j) {
            float xv = xs[r0 + j][k];
            acc[j][0] += xv * w.x;
            acc[j][1] += xv * w.y;
            acc[j][2] += xv * w.z;
            acc[j][3] += xv * w.w;
        }
    }
#pragma unroll
    for (int j = 0; j < 4; ++j) {
        int row = row0 + r0 + j;
        float dinv = rsqrtf((float)deg[row]);
        float4 v = make_float4(acc[j][0] * dinv, acc[j][1] * dinv,
                               acc[j][2] * dinv, acc[j][3] * dinv);
        *(float4*)&g[(size_t)row * DD + c0] = v;
        *(float4*)&out[(size_t)row * DD + c0] = v;
    }
}

// 32 threads per edge, each handles 4 consecutive floats: gather g[src], atomicAdd into out[dst].
__global__ __launch_bounds__(256) void k_scatter(
    const int* __restrict__ src, const int* __restrict__ dst,
    const float* __restrict__ g, float* __restrict__ out) {
    unsigned long long idx = (unsigned long long)blockIdx.x * 256 + threadIdx.x;
    unsigned e = (unsigned)(idx >> 5);
    if (e >= NE) return;
    int lane4 = ((int)idx & 31) * 4;
    int s = src[e], t = dst[e];
    float4 gv = *(const float4*)&g[(size_t)s * DD + lane4];
    float* op = &out[(size_t)t * DD + lane4];
    atomicAdd(op + 0, gv.x);
    atomicAdd(op + 1, gv.y);
    atomicAdd(op + 2, gv.z);
    atomicAdd(op + 3, gv.w);
}

// out = relu(rsqrt(deg[row]) * acc + b)
__global__ __launch_bounds__(256) void k_finalize(
    float* __restrict__ out, const int* __restrict__ deg, const float* __restrict__ b) {
    int idx = blockIdx.x * 256 + threadIdx.x;
    if (idx >= NN * DD / 4) return;
    int row = idx >> 5;
    int c0 = (idx & 31) * 4;
    float dinv = rsqrtf((float)deg[row]);
    float4 v = ((float4*)out)[idx];
    const float4 bb = *(const float4*)&b[c0];
    v.x = fmaxf(fmaf(v.x, dinv, bb.x), 0.f);
    v.y = fmaxf(fmaf(v.y, dinv, bb.y), 0.f);
    v.z = fmaxf(fmaf(v.z, dinv, bb.z), 0.f);
    v.w = fmaxf(fmaf(v.w, dinv, bb.w), 0.f);
    ((float4*)out)[idx] = v;
}

extern "C" void kernel_launch(void* const* d_in, const int* in_sizes, int n_in,
                              void* d_out, int out_size, void* d_ws, size_t ws_size,
                              hipStream_t stream) {
    const float* x = (const float*)d_in[0];
    const int* edge = (const int*)d_in[1];
    const float* W = (const float*)d_in[2];
    const float* b = (const float*)d_in[3];
    float* out = (float*)d_out;

    int* deg = (int*)d_ws;                              // 400 KB
    float* g = (float*)((char*)d_ws + (1 << 20));       // 51.2 MB at +1MB

    const int* src = edge;        // edge_index[0]
    const int* dst = edge + NE;   // edge_index[1]

    k_init_deg<<<(NN + 255) / 256, 256, 0, stream>>>(deg);
    k_count_deg<<<(NE + 255) / 256, 256, 0, stream>>>(dst, deg);
    k_gemm_scale<<<NN / 32, 256, 0, stream>>>(x, W, deg, g, out);
    k_scatter<<<(int)(((unsigned long long)NE * 32 + 255) / 256), 256, 0, stream>>>(src, dst, g, out);
    k_finalize<<<(NN * DD / 4 + 255) / 256, 256, 0, stream>>>(out, deg, b);
}

// Round 2
// 770.430 us; speedup vs baseline: 7.2261x; 7.2261x over previous
//
#include <hip/hip_runtime.h>

#define NN 100000
#define NE 3200000
#define DD 128

// ---------------- workspace layout ----------------
// [0      , 400KB) cnt   (int NN)  = in-degree (excl. self loop)
// [512KB  , ...  ) start (int NN)  = exclusive prefix sum of cnt
// [1MB    , ...  ) fill  (int NN)  = sort cursors
// [2MB    , +12.8MB) esrc (int NE) = src ids sorted by dst
// [16MB   , +51.2MB) g   (float NN*DD) = (x@W) * rsqrt(deg)

__global__ __launch_bounds__(256) void k_zero(int* __restrict__ cnt, int* __restrict__ fill) {
    int i = blockIdx.x * 256 + threadIdx.x;
    if (i < NN) { cnt[i] = 0; fill[i] = 0; }
}

__global__ __launch_bounds__(256) void k_hist(const int* __restrict__ dst, int* __restrict__ cnt) {
    int e = blockIdx.x * 256 + threadIdx.x;
    if (e < NE) atomicAdd(&cnt[dst[e]], 1);
}

// single-block exclusive scan over NN counts: thread t owns a contiguous chunk
__global__ __launch_bounds__(256) void k_scan(const int* __restrict__ cnt, int* __restrict__ start) {
    __shared__ int ssum[256];
    const int per = (NN + 255) / 256;  // 391
    int t = threadIdx.x;
    int lo = t * per;
    int hi = lo + per; if (hi > NN) hi = NN;
    int s = 0;
    for (int i = lo; i < hi; ++i) s += cnt[i];
    ssum[t] = s;
    __syncthreads();
    // Hillis-Steele inclusive scan (in place, double-barrier per step)
    for (int off = 1; off < 256; off <<= 1) {
        int v = (t >= off) ? ssum[t - off] : 0;
        __syncthreads();
        ssum[t] += v;
        __syncthreads();
    }
    int run = (t == 0) ? 0 : ssum[t - 1];
    for (int i = lo; i < hi; ++i) { start[i] = run; run += cnt[i]; }
}

// counting-sort scatter: place src id of each edge into its dst segment
__global__ __launch_bounds__(256) void k_sort(const int* __restrict__ src, const int* __restrict__ dst,
                                              const int* __restrict__ start, int* __restrict__ fill,
                                              int* __restrict__ esrc) {
    int e = blockIdx.x * 256 + threadIdx.x;
    if (e >= NE) return;
    int d = dst[e];
    int p = start[d] + atomicAdd(&fill[d], 1);
    esrc[p] = src[e];
}

// g = (x @ W) * rsqrt(deg); deg = cnt+1. 32-row x 128-col tile, W in LDS.
__global__ __launch_bounds__(256) void k_gemm_scale(
    const float* __restrict__ x, const float* __restrict__ W,
    const int* __restrict__ cnt, float* __restrict__ g) {
    __shared__ float Wl[DD * DD];    // 64 KB
    __shared__ float xs[32][DD];     // 16 KB
    for (int t = threadIdx.x; t < DD * DD / 4; t += 256)
        ((float4*)Wl)[t] = ((const float4*)W)[t];
    const int row0 = blockIdx.x * 32;
    {
        const float4* xv = (const float4*)(x + (size_t)row0 * DD);
        float4* xsv = (float4*)&xs[0][0];
        for (int v = threadIdx.x; v < 32 * DD / 4; v += 256) xsv[v] = xv[v];
    }
    __syncthreads();
    const int tx = threadIdx.x & 31;
    const int ty = threadIdx.x >> 5;
    const int c0 = tx * 4;
    const int r0 = ty * 4;
    float acc[4][4] = {};
#pragma unroll 4
    for (int k = 0; k < DD; ++k) {
        float4 w = *(const float4*)&Wl[k * DD + c0];
#pragma unroll
        for (int j = 0; j < 4; ++j) {
            float xv = xs[r0 + j][k];
            acc[j][0] += xv * w.x;
            acc[j][1] += xv * w.y;
            acc[j][2] += xv * w.z;
            acc[j][3] += xv * w.w;
        }
    }
#pragma unroll
    for (int j = 0; j < 4; ++j) {
        int row = row0 + r0 + j;
        float dinv = rsqrtf((float)(cnt[row] + 1));
        float4 v = make_float4(acc[j][0] * dinv, acc[j][1] * dinv,
                               acc[j][2] * dinv, acc[j][3] * dinv);
        *(float4*)&g[(size_t)row * DD + c0] = v;
    }
}

// one wave per dst node: acc = g[node] + sum_j g[esrc[j]]; out = relu(dinv*acc + b)
__global__ __launch_bounds__(256) void k_aggregate(
    const float* __restrict__ g, const int* __restrict__ esrc,
    const int* __restrict__ start, const int* __restrict__ cnt,
    const float* __restrict__ b, float* __restrict__ out) {
    int node = blockIdx.x * 4 + (threadIdx.x >> 6);
    if (node >= NN) return;
    int lane = threadIdx.x & 63;
    int c0 = lane * 2;
    float2 acc = *(const float2*)&g[(size_t)node * DD + c0];  // self-loop term
    int base = start[node];
    int n = cnt[node];
    int j = 0;
    for (; j + 4 <= n; j += 4) {  // unroll x4 to pipeline gathers
        int s0 = esrc[base + j + 0];
        int s1 = esrc[base + j + 1];
        int s2 = esrc[base + j + 2];
        int s3 = esrc[base + j + 3];
        float2 v0 = *(const float2*)&g[(size_t)s0 * DD + c0];
        float2 v1 = *(const float2*)&g[(size_t)s1 * DD + c0];
        float2 v2 = *(const float2*)&g[(size_t)s2 * DD + c0];
        float2 v3 = *(const float2*)&g[(size_t)s3 * DD + c0];
        acc.x += v0.x + v1.x + v2.x + v3.x;
        acc.y += v0.y + v1.y + v2.y + v3.y;
    }
    for (; j < n; ++j) {
        int s = esrc[base + j];
        float2 v = *(const float2*)&g[(size_t)s * DD + c0];
        acc.x += v.x; acc.y += v.y;
    }
    float dinv = rsqrtf((float)(n + 1));
    float2 bb = *(const float2*)&b[c0];
    float2 o;
    o.x = fmaxf(fmaf(acc.x, dinv, bb.x), 0.f);
    o.y = fmaxf(fmaf(acc.y, dinv, bb.y), 0.f);
    *(float2*)&out[(size_t)node * DD + c0] = o;
}

extern "C" void kernel_launch(void* const* d_in, const int* in_sizes, int n_in,
                              void* d_out, int out_size, void* d_ws, size_t ws_size,
                              hipStream_t stream) {
    const float* x = (const float*)d_in[0];
    const int* edge = (const int*)d_in[1];
    const float* W = (const float*)d_in[2];
    const float* b = (const float*)d_in[3];
    float* out = (float*)d_out;

    int* cnt   = (int*)d_ws;
    int* start = (int*)((char*)d_ws + (512 << 10));
    int* fill  = (int*)((char*)d_ws + (1 << 20));
    int* esrc  = (int*)((char*)d_ws + (2 << 20));
    float* g   = (float*)((char*)d_ws + (16 << 20));

    const int* src = edge;        // edge_index[0]
    const int* dst = edge + NE;   // edge_index[1]

    k_zero<<<(NN + 255) / 256, 256, 0, stream>>>(cnt, fill);
    k_hist<<<(NE + 255) / 256, 256, 0, stream>>>(dst, cnt);
    k_scan<<<1, 256, 0, stream>>>(cnt, start);
    k_sort<<<(NE + 255) / 256, 256, 0, stream>>>(src, dst, start, fill, esrc);
    k_gemm_scale<<<NN / 32, 256, 0, stream>>>(x, W, cnt, g);
    k_aggregate<<<(NN + 3) / 4, 256, 0, stream>>>(g, esrc, start, cnt, b, out);
}

// Round 3
// 479.295 us; speedup vs baseline: 11.6154x; 1.6074x over previous
//
#include <hip/hip_runtime.h>

#define NN 100000
#define NE 3200000
#define DD 128
#define NSHARD 8
#define SHARD_NODES (NN / NSHARD)   // 12500
#define NCHUNK 128
#define CHUNK_EDGES (NE / NCHUNK)   // 25000
#define SCAN_BLK 98                 // ceil(NN/1024)

// ---------------- workspace layout ----------------
// cnt   @ 0      (int NN)   in-degree excl self loop
// start @ 512KB  (int NN)   exclusive prefix of cnt
// fill  @ 1MB    (int NN)   sort cursors (init = start)
// bsum  @ 1536KB (int 98)   scan partials
// bpre  @ 1600KB (int 98)   scanned partials
// esrc  @ 2MB    (int NE)   src ids sorted by dst
// g     @ 16MB   (uint NN*64) bf16x2-packed (x@W)*rsqrt(deg)

__device__ inline unsigned bf16pair(float a, float b) {
    unsigned ua = __float_as_uint(a); ua = (ua + 0x7fffu + ((ua >> 16) & 1u)) >> 16;
    unsigned ub = __float_as_uint(b); ub = (ub + 0x7fffu + ((ub >> 16) & 1u)) >> 16;
    return ua | (ub << 16);
}
__device__ inline float bflo(unsigned u) { return __uint_as_float(u << 16); }
__device__ inline float bfhi(unsigned u) { return __uint_as_float(u & 0xffff0000u); }

__global__ __launch_bounds__(256) void k_zero(int* __restrict__ cnt) {
    int i = blockIdx.x * 256 + threadIdx.x;
    if (i < NN) cnt[i] = 0;
}

__global__ __launch_bounds__(256) void k_hist(const int* __restrict__ dst, int* __restrict__ cnt) {
    int e = blockIdx.x * 256 + threadIdx.x;
    if (e < NE) atomicAdd(&cnt[dst[e]], 1);
}

// scan step 1: per-block (1024 elems) sums
__global__ __launch_bounds__(256) void k_scan1(const int* __restrict__ cnt, int* __restrict__ bsum) {
    __shared__ int red[256];
    int base = blockIdx.x * 1024 + threadIdx.x * 4;
    int s = 0;
#pragma unroll
    for (int j = 0; j < 4; ++j) { int i = base + j; if (i < NN) s += cnt[i]; }
    red[threadIdx.x] = s;
    __syncthreads();
    for (int off = 128; off > 0; off >>= 1) {
        if (threadIdx.x < off) red[threadIdx.x] += red[threadIdx.x + off];
        __syncthreads();
    }
    if (threadIdx.x == 0) bsum[blockIdx.x] = red[0];
}

// scan step 2: exclusive scan of the 98 block sums (single block)
__global__ __launch_bounds__(128) void k_scan2(const int* __restrict__ bsum, int* __restrict__ bpre) {
    __shared__ int s[128];
    int t = threadIdx.x;
    s[t] = (t < SCAN_BLK) ? bsum[t] : 0;
    __syncthreads();
    for (int off = 1; off < 128; off <<= 1) {
        int v = (t >= off) ? s[t - off] : 0;
        __syncthreads();
        s[t] += v;
        __syncthreads();
    }
    if (t < SCAN_BLK) bpre[t] = (t == 0) ? 0 : s[t - 1];
}

// scan step 3: emit start[] and fill[] (= start)
__global__ __launch_bounds__(256) void k_scan3(const int* __restrict__ cnt, const int* __restrict__ bpre,
                                               int* __restrict__ start, int* __restrict__ fill) {
    __shared__ int s[256];
    int t = threadIdx.x;
    int base = blockIdx.x * 1024 + t * 4;
    int c[4]; int ts = 0;
#pragma unroll
    for (int j = 0; j < 4; ++j) { int i = base + j; c[j] = (i < NN) ? cnt[i] : 0; ts += c[j]; }
    s[t] = ts;
    __syncthreads();
    for (int off = 1; off < 256; off <<= 1) {
        int v = (t >= off) ? s[t - off] : 0;
        __syncthreads();
        s[t] += v;
        __syncthreads();
    }
    int run = bpre[blockIdx.x] + ((t == 0) ? 0 : s[t - 1]);
#pragma unroll
    for (int j = 0; j < 4; ++j) {
        int i = base + j;
        if (i < NN) { start[i] = run; fill[i] = run; run += c[j]; }
    }
}

// g = (x @ W) * rsqrt(deg), packed bf16x2. 32-row x 128-col tile, W in LDS.
__global__ __launch_bounds__(256) void k_gemm_scale(
    const float* __restrict__ x, const float* __restrict__ W,
    const int* __restrict__ cnt, unsigned* __restrict__ g) {
    __shared__ float Wl[DD * DD];    // 64 KB
    __shared__ float xs[32][DD];     // 16 KB
    for (int t = threadIdx.x; t < DD * DD / 4; t += 256)
        ((float4*)Wl)[t] = ((const float4*)W)[t];
    const int row0 = blockIdx.x * 32;
    {
        const float4* xv = (const float4*)(x + (size_t)row0 * DD);
        float4* xsv = (float4*)&xs[0][0];
        for (int v = threadIdx.x; v < 32 * DD / 4; v += 256) xsv[v] = xv[v];
    }
    __syncthreads();
    const int tx = threadIdx.x & 31;
    const int ty = threadIdx.x >> 5;
    const int c0 = tx * 4;
    const int r0 = ty * 4;
    float acc[4][4] = {};
#pragma unroll 4
    for (int k = 0; k < DD; ++k) {
        float4 w = *(const float4*)&Wl[k * DD + c0];
#pragma unroll
        for (int j = 0; j < 4; ++j) {
            float xv = xs[r0 + j][k];
            acc[j][0] += xv * w.x;
            acc[j][1] += xv * w.y;
            acc[j][2] += xv * w.z;
            acc[j][3] += xv * w.w;
        }
    }
#pragma unroll
    for (int j = 0; j < 4; ++j) {
        int row = row0 + r0 + j;
        float dinv = rsqrtf((float)(cnt[row] + 1));
        uint2 v;
        v.x = bf16pair(acc[j][0] * dinv, acc[j][1] * dinv);
        v.y = bf16pair(acc[j][2] * dinv, acc[j][3] * dinv);
        *(uint2*)&g[(size_t)row * 64 + tx * 2] = v;
    }
}

// XCD-sharded counting-sort scatter: block handles shard (blockIdx&7) of dst space
// over its edge chunk. Each XCD's esrc slice (1.6MB) + fill slice (50KB) stay L2-local
// so 4B writes merge into full lines before eviction.
__global__ __launch_bounds__(256) void k_sort(const int* __restrict__ src, const int* __restrict__ dst,
                                              int* __restrict__ fill, int* __restrict__ esrc) {
    const int shard = blockIdx.x & (NSHARD - 1);
    const int chunk = blockIdx.x >> 3;
    const int lo = shard * SHARD_NODES;
    const int hi = lo + SHARD_NODES;
    const int base = chunk * CHUNK_EDGES;
    for (int it = threadIdx.x; it < CHUNK_EDGES; it += 256) {
        int e = base + it;
        int d = dst[e];
        if (d >= lo && d < hi) {
            int p = atomicAdd(&fill[d], 1);
            esrc[p] = src[e];
        }
    }
}

// one wave per dst node: acc = g[node] + sum_j g[esrc[j]]; out = relu(dinv*acc + b)
__global__ __launch_bounds__(256) void k_aggregate(
    const unsigned* __restrict__ g, const int* __restrict__ esrc,
    const int* __restrict__ start, const int* __restrict__ cnt,
    const float* __restrict__ b, float* __restrict__ out) {
    int node = blockIdx.x * 4 + (threadIdx.x >> 6);
    if (node >= NN) return;
    int lane = threadIdx.x & 63;
    const unsigned* gl = g + lane;   // one uint (2 bf16) per lane; 64 lanes = row
    unsigned u0 = gl[(size_t)node * 64];
    float ax = bflo(u0), ay = bfhi(u0);
    int base = start[node];
    int n = cnt[node];
    int j = 0;
    for (; j + 4 <= n; j += 4) {
        int s0 = esrc[base + j + 0];
        int s1 = esrc[base + j + 1];
        int s2 = esrc[base + j + 2];
        int s3 = esrc[base + j + 3];
        unsigned v0 = gl[(size_t)s0 * 64];
        unsigned v1 = gl[(size_t)s1 * 64];
        unsigned v2 = gl[(size_t)s2 * 64];
        unsigned v3 = gl[(size_t)s3 * 64];
        ax += bflo(v0) + bflo(v1) + bflo(v2) + bflo(v3);
        ay += bfhi(v0) + bfhi(v1) + bfhi(v2) + bfhi(v3);
    }
    for (; j < n; ++j) {
        unsigned v = gl[(size_t)esrc[base + j] * 64];
        ax += bflo(v); ay += bfhi(v);
    }
    float dinv = rsqrtf((float)(n + 1));
    float2 bb = *(const float2*)&b[lane * 2];
    float2 o;
    o.x = fmaxf(fmaf(ax, dinv, bb.x), 0.f);
    o.y = fmaxf(fmaf(ay, dinv, bb.y), 0.f);
    *(float2*)&out[(size_t)node * DD + lane * 2] = o;
}

extern "C" void kernel_launch(void* const* d_in, const int* in_sizes, int n_in,
                              void* d_out, int out_size, void* d_ws, size_t ws_size,
                              hipStream_t stream) {
    const float* x = (const float*)d_in[0];
    const int* edge = (const int*)d_in[1];
    const float* W = (const float*)d_in[2];
    const float* b = (const float*)d_in[3];
    float* out = (float*)d_out;

    int* cnt      = (int*)d_ws;
    int* start    = (int*)((char*)d_ws + (512 << 10));
    int* fill     = (int*)((char*)d_ws + (1 << 20));
    int* bsum     = (int*)((char*)d_ws + (1536 << 10));
    int* bpre     = (int*)((char*)d_ws + (1600 << 10));
    int* esrc     = (int*)((char*)d_ws + (2 << 20));
    unsigned* g   = (unsigned*)((char*)d_ws + (16 << 20));

    const int* src = edge;        // edge_index[0]
    const int* dst = edge + NE;   // edge_index[1]

    k_zero<<<(NN + 255) / 256, 256, 0, stream>>>(cnt);
    k_hist<<<(NE + 255) / 256, 256, 0, stream>>>(dst, cnt);
    k_scan1<<<SCAN_BLK, 256, 0, stream>>>(cnt, bsum);
    k_scan2<<<1, 128, 0, stream>>>(bsum, bpre);
    k_scan3<<<SCAN_BLK, 256, 0, stream>>>(cnt, bpre, start, fill);
    k_gemm_scale<<<NN / 32, 256, 0, stream>>>(x, W, cnt, g);
    k_sort<<<NSHARD * NCHUNK, 256, 0, stream>>>(src, dst, fill, esrc);
    k_aggregate<<<(NN + 3) / 4, 256, 0, stream>>>(g, esrc, start, cnt, b, out);
}

// Round 4
// 271.796 us; speedup vs baseline: 20.4830x; 1.7634x over previous
//
#include <hip/hip_runtime.h>

#define NN 100000
#define NE 3200000
#define DD 128
#define NB 391                 // coarse buckets: dst>>8 (256 nodes each)
#define NCH 512                // edge chunks
#define CHUNK (NE / NCH)       // 6250

// ---------------- workspace layout ----------------
// cnt   @ 0        (int NN)      in-degree excl self loop
// start @ 400KB    (int NN)      global CSR offsets
// BT    @ 800KB    (int NB)      bucket totals
// BB    @ 804KB    (int NB)      bucket bases (exclusive scan of BT)
// H     @ 1MB      (int NCH*NB)  per-chunk bucket hist -> within-bucket offsets
// esrc  @ 2MB      (int NE)      src ids sorted by dst           [ends 14.8MB]
// P     @ 15MB     (int2 NE)     coarse-partitioned (src,dst)    [ends 40.6MB]
// g     @ 15MB     (uint NN*64)  bf16x2 packed (x@W)*dinv — ALIASES P (P dead before gemm)

__device__ inline unsigned bf16pair(float a, float b) {
    unsigned ua = __float_as_uint(a); ua = (ua + 0x7fffu + ((ua >> 16) & 1u)) >> 16;
    unsigned ub = __float_as_uint(b); ub = (ub + 0x7fffu + ((ub >> 16) & 1u)) >> 16;
    return ua | (ub << 16);
}
__device__ inline float bflo(unsigned u) { return __uint_as_float(u << 16); }
__device__ inline float bfhi(unsigned u) { return __uint_as_float(u & 0xffff0000u); }

// pass A: per-chunk coarse histogram (LDS), write H[chunk][bucket]
__global__ __launch_bounds__(256) void k_hist1(const int* __restrict__ dst, int* __restrict__ H) {
    __shared__ int h[NB];
    for (int i = threadIdx.x; i < NB; i += 256) h[i] = 0;
    __syncthreads();
    const int base = blockIdx.x * CHUNK;
    for (int i = threadIdx.x; i < CHUNK; i += 256)
        atomicAdd(&h[dst[base + i] >> 8], 1);
    __syncthreads();
    for (int i = threadIdx.x; i < NB; i += 256) H[blockIdx.x * NB + i] = h[i];
}

// pass B1: per bucket, scan H column over chunks -> within-bucket chunk offsets (in place) + BT
__global__ __launch_bounds__(512) void k_offB1(int* __restrict__ H, int* __restrict__ BT) {
    __shared__ int s[512];
    const int b = blockIdx.x;
    const int t = threadIdx.x;
    int v = H[t * NB + b];
    s[t] = v;
    __syncthreads();
    for (int off = 1; off < 512; off <<= 1) {
        int u = (t >= off) ? s[t - off] : 0;
        __syncthreads();
        s[t] += u;
        __syncthreads();
    }
    H[t * NB + b] = s[t] - v;           // exclusive within-bucket offset for chunk t
    if (t == 511) BT[b] = s[511];
}

// pass B2: exclusive scan of BT -> BB (single block)
__global__ __launch_bounds__(512) void k_offB2(const int* __restrict__ BT, int* __restrict__ BB) {
    __shared__ int s[512];
    const int t = threadIdx.x;
    int v = (t < NB) ? BT[t] : 0;
    s[t] = v;
    __syncthreads();
    for (int off = 1; off < 512; off <<= 1) {
        int u = (t >= off) ? s[t - off] : 0;
        __syncthreads();
        s[t] += u;
        __syncthreads();
    }
    if (t < NB) BB[t] = s[t] - v;
}

// pass C: stable coarse partition, LDS cursors, zero global atomics
__global__ __launch_bounds__(256) void k_part(const int* __restrict__ src, const int* __restrict__ dst,
                                              const int* __restrict__ H, const int* __restrict__ BB,
                                              int2* __restrict__ P) {
    __shared__ int cur[NB];
    for (int i = threadIdx.x; i < NB; i += 256)
        cur[i] = BB[i] + H[blockIdx.x * NB + i];
    __syncthreads();
    const int base = blockIdx.x * CHUNK;
    for (int i = threadIdx.x; i < CHUNK; i += 256) {
        int s = src[base + i];
        int d = dst[base + i];
        int p = atomicAdd(&cur[d >> 8], 1);   // LDS atomic
        P[p] = make_int2(s, d);
    }
}

// pass D: per-bucket LDS counting sort (256-node range); emits esrc + cnt + start
__global__ __launch_bounds__(256) void k_bsort(const int2* __restrict__ P, const int* __restrict__ BB,
                                               const int* __restrict__ BT, int* __restrict__ esrc,
                                               int* __restrict__ cnt, int* __restrict__ start) {
    __shared__ int hist[256], red[256], sexcl[256], fil[256];
    const int b = blockIdx.x;
    const int base = BB[b];
    const int n = BT[b];
    const int t = threadIdx.x;
    hist[t] = 0;
    __syncthreads();
    for (int i = t; i < n; i += 256)
        atomicAdd(&hist[P[base + i].y & 255], 1);
    __syncthreads();
    int c = hist[t];
    red[t] = c;
    __syncthreads();
    for (int off = 1; off < 256; off <<= 1) {
        int u = (t >= off) ? red[t - off] : 0;
        __syncthreads();
        red[t] += u;
        __syncthreads();
    }
    int excl = red[t] - c;
    sexcl[t] = excl;
    fil[t] = 0;
    int node = (b << 8) + t;
    if (node < NN) { cnt[node] = c; start[node] = base + excl; }
    __syncthreads();
    for (int i = t; i < n; i += 256) {
        int2 p = P[base + i];
        int dl = p.y & 255;
        int pos = atomicAdd(&fil[dl], 1);     // LDS atomic
        esrc[base + sexcl[dl] + pos] = p.x;
    }
}

// g = (x @ W) * rsqrt(deg), packed bf16x2. 32-row x 128-col tile, W in LDS.
__global__ __launch_bounds__(256) void k_gemm_scale(
    const float* __restrict__ x, const float* __restrict__ W,
    const int* __restrict__ cnt, unsigned* __restrict__ g) {
    __shared__ float Wl[DD * DD];    // 64 KB
    __shared__ float xs[32][DD];     // 16 KB
    for (int t = threadIdx.x; t < DD * DD / 4; t += 256)
        ((float4*)Wl)[t] = ((const float4*)W)[t];
    const int row0 = blockIdx.x * 32;
    {
        const float4* xv = (const float4*)(x + (size_t)row0 * DD);
        float4* xsv = (float4*)&xs[0][0];
        for (int v = threadIdx.x; v < 32 * DD / 4; v += 256) xsv[v] = xv[v];
    }
    __syncthreads();
    const int tx = threadIdx.x & 31;
    const int ty = threadIdx.x >> 5;
    const int c0 = tx * 4;
    const int r0 = ty * 4;
    float acc[4][4] = {};
#pragma unroll 4
    for (int k = 0; k < DD; ++k) {
        float4 w = *(const float4*)&Wl[k * DD + c0];
#pragma unroll
        for (int j = 0; j < 4; ++j) {
            float xv = xs[r0 + j][k];
            acc[j][0] += xv * w.x;
            acc[j][1] += xv * w.y;
            acc[j][2] += xv * w.z;
            acc[j][3] += xv * w.w;
        }
    }
#pragma unroll
    for (int j = 0; j < 4; ++j) {
        int row = row0 + r0 + j;
        float dinv = rsqrtf((float)(cnt[row] + 1));
        uint2 v;
        v.x = bf16pair(acc[j][0] * dinv, acc[j][1] * dinv);
        v.y = bf16pair(acc[j][2] * dinv, acc[j][3] * dinv);
        *(uint2*)&g[(size_t)row * 64 + tx * 2] = v;
    }
}

// one wave per dst node: acc = g[node] + sum_j g[esrc[j]]; out = relu(dinv*acc + b)
__global__ __launch_bounds__(256) void k_aggregate(
    const unsigned* __restrict__ g, const int* __restrict__ esrc,
    const int* __restrict__ start, const int* __restrict__ cnt,
    const float* __restrict__ b, float* __restrict__ out) {
    int node = blockIdx.x * 4 + (threadIdx.x >> 6);
    if (node >= NN) return;
    int lane = threadIdx.x & 63;
    const unsigned* gl = g + lane;   // one uint (2 bf16) per lane; 64 lanes = row
    unsigned u0 = gl[(size_t)node * 64];
    float ax = bflo(u0), ay = bfhi(u0);
    int base = start[node];
    int n = cnt[node];
    int j = 0;
    for (; j + 4 <= n; j += 4) {
        int s0 = esrc[base + j + 0];
        int s1 = esrc[base + j + 1];
        int s2 = esrc[base + j + 2];
        int s3 = esrc[base + j + 3];
        unsigned v0 = gl[(size_t)s0 * 64];
        unsigned v1 = gl[(size_t)s1 * 64];
        unsigned v2 = gl[(size_t)s2 * 64];
        unsigned v3 = gl[(size_t)s3 * 64];
        ax += bflo(v0) + bflo(v1) + bflo(v2) + bflo(v3);
        ay += bfhi(v0) + bfhi(v1) + bfhi(v2) + bfhi(v3);
    }
    for (; j < n; ++j) {
        unsigned v = gl[(size_t)esrc[base + j] * 64];
        ax += bflo(v); ay += bfhi(v);
    }
    float dinv = rsqrtf((float)(n + 1));
    float2 bb = *(const float2*)&b[lane * 2];
    float2 o;
    o.x = fmaxf(fmaf(ax, dinv, bb.x), 0.f);
    o.y = fmaxf(fmaf(ay, dinv, bb.y), 0.f);
    *(float2*)&out[(size_t)node * DD + lane * 2] = o;
}

extern "C" void kernel_launch(void* const* d_in, const int* in_sizes, int n_in,
                              void* d_out, int out_size, void* d_ws, size_t ws_size,
                              hipStream_t stream) {
    const float* x = (const float*)d_in[0];
    const int* edge = (const int*)d_in[1];
    const float* W = (const float*)d_in[2];
    const float* b = (const float*)d_in[3];
    float* out = (float*)d_out;

    char* ws = (char*)d_ws;
    int* cnt    = (int*)(ws);
    int* start  = (int*)(ws + 400 * 1024);
    int* BT     = (int*)(ws + 800 * 1024);
    int* BB     = (int*)(ws + 804 * 1024);
    int* H      = (int*)(ws + (1 << 20));
    int* esrc   = (int*)(ws + (2 << 20));
    int2* P     = (int2*)(ws + (15ull << 20));
    unsigned* g = (unsigned*)(ws + (15ull << 20));   // aliases P: P dead before k_gemm_scale

    const int* src = edge;        // edge_index[0]
    const int* dst = edge + NE;   // edge_index[1]

    k_hist1<<<NCH, 256, 0, stream>>>(dst, H);
    k_offB1<<<NB, 512, 0, stream>>>(H, BT);
    k_offB2<<<1, 512, 0, stream>>>(BT, BB);
    k_part<<<NCH, 256, 0, stream>>>(src, dst, H, BB, P);
    k_bsort<<<NB, 256, 0, stream>>>(P, BB, BT, esrc, cnt, start);
    k_gemm_scale<<<NN / 32, 256, 0, stream>>>(x, W, cnt, g);
    k_aggregate<<<(NN + 3) / 4, 256, 0, stream>>>(g, esrc, start, cnt, b, out);
}

// Round 5
// 214.890 us; speedup vs baseline: 25.9072x; 1.2648x over previous
//
#include <hip/hip_runtime.h>

#define NN 100000
#define NE 3200000
#define DD 128
#define NB 391                 // coarse buckets: dst>>8 (256 nodes each)
#define NCH 512                // edge chunks
#define CHUNK (NE / NCH)       // 6250

// ---------------- workspace layout ----------------
// cnt   @ 0        (int NN)      in-degree excl self loop
// start @ 400KB    (int NN)      global CSR offsets
// BT    @ 800KB    (int NB)      bucket totals
// BB    @ 804KB    (int NB)      bucket bases
// Wimg  @ 832KB    (u32 8192)    bf16 W^T, XOR-swizzled LDS image (32KB)
// H     @ 1MB      (int NCH*NB)  per-chunk bucket hist -> within-bucket offsets
// esrc  @ 2MB      (int NE)      src ids sorted by dst           [ends 14.8MB]
// P     @ 15MB     (int2 NE)     coarse-partitioned (src,dst)
// g     @ 15MB     (u32 NN*64)   bf16x2 (cols i,i+64) of (x@W)*dinv — aliases P

typedef __attribute__((ext_vector_type(8))) short bf16x8;
typedef __attribute__((ext_vector_type(4))) float f32x4;

__device__ inline unsigned bf16pair(float a, float b) {
    unsigned ua = __float_as_uint(a); ua = (ua + 0x7fffu + ((ua >> 16) & 1u)) >> 16;
    unsigned ub = __float_as_uint(b); ub = (ub + 0x7fffu + ((ub >> 16) & 1u)) >> 16;
    return ua | (ub << 16);
}
__device__ inline float bflo(unsigned u) { return __uint_as_float(u << 16); }
__device__ inline float bfhi(unsigned u) { return __uint_as_float(u & 0xffff0000u); }

// build swizzled bf16 W^T image: Wimg[col][k], byte = col*256 + ((2k) ^ ((col&7)<<4))
__global__ __launch_bounds__(256) void k_wimg(const float* __restrict__ W, unsigned* __restrict__ Wimg) {
    int i = blockIdx.x * 256 + threadIdx.x;   // 8192 = 128 cols x 64 k-pairs
    if (i >= 8192) return;
    int c = i >> 6, k2 = i & 63;
    unsigned v = bf16pair(W[(size_t)(k2 * 2) * DD + c], W[(size_t)(k2 * 2 + 1) * DD + c]);
    int byte = c * 256 + ((k2 * 4) ^ ((c & 7) << 4));
    *(unsigned*)((char*)Wimg + byte) = v;
}

// pass A: per-chunk coarse histogram (LDS), write H[chunk][bucket]
__global__ __launch_bounds__(256) void k_hist1(const int* __restrict__ dst, int* __restrict__ H) {
    __shared__ int h[NB];
    for (int i = threadIdx.x; i < NB; i += 256) h[i] = 0;
    __syncthreads();
    const int base = blockIdx.x * CHUNK;
    for (int i = threadIdx.x; i < CHUNK; i += 256)
        atomicAdd(&h[dst[base + i] >> 8], 1);
    __syncthreads();
    for (int i = threadIdx.x; i < NB; i += 256) H[blockIdx.x * NB + i] = h[i];
}

// pass B1: per bucket, scan H column over chunks -> within-bucket chunk offsets + BT
__global__ __launch_bounds__(512) void k_offB1(int* __restrict__ H, int* __restrict__ BT) {
    __shared__ int s[512];
    const int b = blockIdx.x;
    const int t = threadIdx.x;
    int v = H[t * NB + b];
    s[t] = v;
    __syncthreads();
    for (int off = 1; off < 512; off <<= 1) {
        int u = (t >= off) ? s[t - off] : 0;
        __syncthreads();
        s[t] += u;
        __syncthreads();
    }
    H[t * NB + b] = s[t] - v;
    if (t == 511) BT[b] = s[511];
}

// pass B2: exclusive scan of BT -> BB
__global__ __launch_bounds__(512) void k_offB2(const int* __restrict__ BT, int* __restrict__ BB) {
    __shared__ int s[512];
    const int t = threadIdx.x;
    int v = (t < NB) ? BT[t] : 0;
    s[t] = v;
    __syncthreads();
    for (int off = 1; off < 512; off <<= 1) {
        int u = (t >= off) ? s[t - off] : 0;
        __syncthreads();
        s[t] += u;
        __syncthreads();
    }
    if (t < NB) BB[t] = s[t] - v;
}

// pass C: stable coarse partition, LDS cursors, zero global atomics
__global__ __launch_bounds__(256) void k_part(const int* __restrict__ src, const int* __restrict__ dst,
                                              const int* __restrict__ H, const int* __restrict__ BB,
                                              int2* __restrict__ P) {
    __shared__ int cur[NB];
    for (int i = threadIdx.x; i < NB; i += 256)
        cur[i] = BB[i] + H[blockIdx.x * NB + i];
    __syncthreads();
    const int base = blockIdx.x * CHUNK;
    for (int i = threadIdx.x; i < CHUNK; i += 256) {
        int s = src[base + i];
        int d = dst[base + i];
        int p = atomicAdd(&cur[d >> 8], 1);   // LDS atomic
        P[p] = make_int2(s, d);
    }
}

// pass D: per-bucket LDS counting sort; emits esrc + cnt + start
__global__ __launch_bounds__(256) void k_bsort(const int2* __restrict__ P, const int* __restrict__ BB,
                                               const int* __restrict__ BT, int* __restrict__ esrc,
                                               int* __restrict__ cnt, int* __restrict__ start) {
    __shared__ int hist[256], red[256], sexcl[256], fil[256];
    const int b = blockIdx.x;
    const int base = BB[b];
    const int n = BT[b];
    const int t = threadIdx.x;
    hist[t] = 0;
    __syncthreads();
    for (int i = t; i < n; i += 256)
        atomicAdd(&hist[P[base + i].y & 255], 1);
    __syncthreads();
    int c = hist[t];
    red[t] = c;
    __syncthreads();
    for (int off = 1; off < 256; off <<= 1) {
        int u = (t >= off) ? red[t - off] : 0;
        __syncthreads();
        red[t] += u;
        __syncthreads();
    }
    int excl = red[t] - c;
    sexcl[t] = excl;
    fil[t] = 0;
    int node = (b << 8) + t;
    if (node < NN) { cnt[node] = c; start[node] = base + excl; }
    __syncthreads();
    for (int i = t; i < n; i += 256) {
        int2 p = P[base + i];
        int dl = p.y & 255;
        int pos = atomicAdd(&fil[dl], 1);     // LDS atomic
        esrc[base + sexcl[dl] + pos] = p.x;
    }
}

// MFMA GEMM: g = bf16(x) @ bf16(W) * rsqrt(deg), packed (col i, i+64) pairs.
// Block = 256 thr = 4 waves, 64 rows. LDS: Wt 32KB (from pre-swizzled image) + xs 16KB.
__global__ __launch_bounds__(256) void k_gemm_mfma(
    const float* __restrict__ x, const unsigned* __restrict__ Wimg,
    const int* __restrict__ cnt, unsigned* __restrict__ g) {
    __shared__ unsigned lds[12288];          // Wl 8192 u32 + Xl 4096 u32
    unsigned* Wl = lds;
    unsigned* Xl = lds + 8192;
    const int tid = threadIdx.x;
    // stage W image (already swizzled/transposed): linear 32KB copy
    {
        const uint4* s4 = (const uint4*)Wimg;
        uint4* d4 = (uint4*)Wl;
        for (int i = tid; i < 2048; i += 256) d4[i] = s4[i];
    }
    // stage x tile (64 rows): fp32 -> bf16, swizzled byte = r*256 + ((2k)^((r&7)<<4))
    const int row0 = blockIdx.x * 64;
    {
        int r = tid >> 2;
        int cchunk = tid & 3;
        int srow = row0 + r; if (srow > NN - 1) srow = NN - 1;
        const float4* xr = (const float4*)(x + (size_t)srow * DD + cchunk * 32);
#pragma unroll
        for (int i = 0; i < 4; ++i) {
            float4 f0 = xr[i * 2], f1 = xr[i * 2 + 1];
            uint4 wv;
            wv.x = bf16pair(f0.x, f0.y); wv.y = bf16pair(f0.z, f0.w);
            wv.z = bf16pair(f1.x, f1.y); wv.w = bf16pair(f1.z, f1.w);
            int byte = r * 256 + (((cchunk * 64) + i * 16) ^ ((r & 7) << 4));
            *(uint4*)((char*)Xl + byte) = wv;
        }
    }
    __syncthreads();
    const int w = tid >> 6;
    const int l = tid & 63;
    const int lr = l & 15, lk = l >> 4;
    // A frags: row (w*16+lr), k = kk*32 + lk*8 .. +8
    bf16x8 a[4];
    {
        int r = w * 16 + lr;
#pragma unroll
        for (int kk = 0; kk < 4; ++kk) {
            int byte = r * 256 + ((kk * 64 + lk * 16) ^ ((r & 7) << 4));
            a[kk] = *(bf16x8*)((char*)Xl + byte);
        }
    }
    f32x4 acc[8];
#pragma unroll
    for (int t = 0; t < 8; ++t) acc[t] = (f32x4){0.f, 0.f, 0.f, 0.f};
#pragma unroll
    for (int t = 0; t < 8; ++t) {
        int c = t * 16 + lr;
#pragma unroll
        for (int kk = 0; kk < 4; ++kk) {
            int byte = c * 256 + ((kk * 64 + lk * 16) ^ ((c & 7) << 4));
            bf16x8 bfr = *(bf16x8*)((char*)Wl + byte);
            acc[t] = __builtin_amdgcn_mfma_f32_16x16x32_bf16(a[kk], bfr, acc[t], 0, 0, 0);
        }
    }
    // epilogue: D row = lk*4+j, col = t*16+lr; pack cols (i, i+64)
#pragma unroll
    for (int j = 0; j < 4; ++j) {
        int row = row0 + w * 16 + lk * 4 + j;
        if (row < NN) {
            float dinv = rsqrtf((float)(cnt[row] + 1));
#pragma unroll
            for (int t = 0; t < 4; ++t) {
                unsigned v = bf16pair(acc[t][j] * dinv, acc[t + 4][j] * dinv);
                g[(size_t)row * 64 + t * 16 + lr] = v;
            }
        }
    }
}

// one wave per dst node: acc = g[node] + sum_j g[esrc[j]]; out = relu(dinv*acc + b)
// lane i owns cols (i, i+64)
__global__ __launch_bounds__(256) void k_aggregate(
    const unsigned* __restrict__ g, const int* __restrict__ esrc,
    const int* __restrict__ start, const int* __restrict__ cnt,
    const float* __restrict__ b, float* __restrict__ out) {
    int node = blockIdx.x * 4 + (threadIdx.x >> 6);
    if (node >= NN) return;
    int lane = threadIdx.x & 63;
    unsigned u0 = g[(unsigned)node * 64u + lane];
    float ax = bflo(u0), ay = bfhi(u0);
    const int base = start[node];
    const int n = cnt[node];
    const int* ep = esrc + base;
    int j = 0;
    for (; j + 8 <= n; j += 8) {
        unsigned o0 = (unsigned)ep[j + 0] * 64u + lane;
        unsigned o1 = (unsigned)ep[j + 1] * 64u + lane;
        unsigned o2 = (unsigned)ep[j + 2] * 64u + lane;
        unsigned o3 = (unsigned)ep[j + 3] * 64u + lane;
        unsigned o4 = (unsigned)ep[j + 4] * 64u + lane;
        unsigned o5 = (unsigned)ep[j + 5] * 64u + lane;
        unsigned o6 = (unsigned)ep[j + 6] * 64u + lane;
        unsigned o7 = (unsigned)ep[j + 7] * 64u + lane;
        unsigned v0 = g[o0], v1 = g[o1], v2 = g[o2], v3 = g[o3];
        unsigned v4 = g[o4], v5 = g[o5], v6 = g[o6], v7 = g[o7];
        ax += bflo(v0) + bflo(v1) + bflo(v2) + bflo(v3)
            + bflo(v4) + bflo(v5) + bflo(v6) + bflo(v7);
        ay += bfhi(v0) + bfhi(v1) + bfhi(v2) + bfhi(v3)
            + bfhi(v4) + bfhi(v5) + bfhi(v6) + bfhi(v7);
    }
    for (; j + 4 <= n; j += 4) {
        unsigned v0 = g[(unsigned)ep[j + 0] * 64u + lane];
        unsigned v1 = g[(unsigned)ep[j + 1] * 64u + lane];
        unsigned v2 = g[(unsigned)ep[j + 2] * 64u + lane];
        unsigned v3 = g[(unsigned)ep[j + 3] * 64u + lane];
        ax += bflo(v0) + bflo(v1) + bflo(v2) + bflo(v3);
        ay += bfhi(v0) + bfhi(v1) + bfhi(v2) + bfhi(v3);
    }
    for (; j < n; ++j) {
        unsigned v = g[(unsigned)ep[j] * 64u + lane];
        ax += bflo(v); ay += bfhi(v);
    }
    float dinv = rsqrtf((float)(n + 1));
    float bx = b[lane], by = b[lane + 64];
    float ox = fmaxf(fmaf(ax, dinv, bx), 0.f);
    float oy = fmaxf(fmaf(ay, dinv, by), 0.f);
    out[(size_t)node * DD + lane] = ox;
    out[(size_t)node * DD + lane + 64] = oy;
}

extern "C" void kernel_launch(void* const* d_in, const int* in_sizes, int n_in,
                              void* d_out, int out_size, void* d_ws, size_t ws_size,
                              hipStream_t stream) {
    const float* x = (const float*)d_in[0];
    const int* edge = (const int*)d_in[1];
    const float* W = (const float*)d_in[2];
    const float* b = (const float*)d_in[3];
    float* out = (float*)d_out;

    char* ws = (char*)d_ws;
    int* cnt      = (int*)(ws);
    int* start    = (int*)(ws + 400 * 1024);
    int* BT       = (int*)(ws + 800 * 1024);
    int* BB       = (int*)(ws + 804 * 1024);
    unsigned* Wim = (unsigned*)(ws + 832 * 1024);
    int* H        = (int*)(ws + (1 << 20));
    int* esrc     = (int*)(ws + (2 << 20));
    int2* P       = (int2*)(ws + (15ull << 20));
    unsigned* g   = (unsigned*)(ws + (15ull << 20));   // aliases P: P dead before gemm

    const int* src = edge;        // edge_index[0]
    const int* dst = edge + NE;   // edge_index[1]

    k_wimg<<<32, 256, 0, stream>>>(W, Wim);
    k_hist1<<<NCH, 256, 0, stream>>>(dst, H);
    k_offB1<<<NB, 512, 0, stream>>>(H, BT);
    k_offB2<<<1, 512, 0, stream>>>(BT, BB);
    k_part<<<NCH, 256, 0, stream>>>(src, dst, H, BB, P);
    k_bsort<<<NB, 256, 0, stream>>>(P, BB, BT, esrc, cnt, start);
    k_gemm_mfma<<<(NN + 63) / 64, 256, 0, stream>>>(x, Wim, cnt, g);
    k_aggregate<<<(NN + 3) / 4, 256, 0, stream>>>(g, esrc, start, cnt, b, out);
}